// Round 1
// 415.782 us; speedup vs baseline: 1.1728x; 1.1728x over previous
//
#include <hip/hip_runtime.h>
#include <math.h>

#define TB     8       // tokens per workgroup
#define CDIM   256
#define NHEADS 4
#define DHEAD  64
#define NV     8
#define LSEQ   8192
#define NB     4

// Fused: LayerNorm(q) -> qk = per-head q@Wk^T -> scores -> softmax ->
// wctx = probs@ctx -> out = per-head wctx@Wv + bv.
// bk is skipped: it adds a per-(t,h) constant to all Nv scores -> cancels in softmax.
// TB=8 / 512 threads: LDS = 41 KB -> 3 blocks/CU (24 waves, 75% occ) so phases of
// different blocks overlap across barriers (was 82 KB -> 1 block/CU, 47% occ).
__global__ __launch_bounds__(512, 6) void triplane_fused(
    const float* __restrict__ q,
    const float* __restrict__ ctx,
    const float* __restrict__ Wk,
    const float* __restrict__ Wv,
    const float* __restrict__ bv,
    const float* __restrict__ gamma,
    const float* __restrict__ beta,
    float* __restrict__ out,
    float* __restrict__ probs_out)
{
    __shared__ float s_qn[TB * CDIM];            // 8 KB; reused as output accumulator
    __shared__ float s_qk[TB * NHEADS * CDIM];   // 32 KB; reused as wctx
    __shared__ float s_sc[TB * NV * NHEADS];     // 1 KB: scores -> probs, layout [t][n][h]

    const int tid  = threadIdx.x;
    const int w    = tid >> 6;    // wave id 0..7
    const int lane = tid & 63;
    const int tok0 = blockIdx.x * TB;

    // ---------- Phase 0: LayerNorm(q) -> s_qn  (wave w <-> token w) ----------
    {
        const int t = w;
        const int c = lane * 4;
        const float4 qv = *reinterpret_cast<const float4*>(q + (size_t)(tok0 + t) * CDIM + c);
        float s  = qv.x + qv.y + qv.z + qv.w;
        float s2 = qv.x*qv.x + qv.y*qv.y + qv.z*qv.z + qv.w*qv.w;
        #pragma unroll
        for (int off = 32; off >= 1; off >>= 1) {
            s  += __shfl_xor(s,  off);
            s2 += __shfl_xor(s2, off);
        }
        const float mu   = s  * (1.0f / CDIM);
        const float var  = s2 * (1.0f / CDIM) - mu * mu;
        const float rstd = rsqrtf(var + 1e-5f);
        const float4 g  = *reinterpret_cast<const float4*>(gamma + c);
        const float4 be = *reinterpret_cast<const float4*>(beta + c);
        float4 qn;
        qn.x = (qv.x - mu) * rstd * g.x + be.x;
        qn.y = (qv.y - mu) * rstd * g.y + be.y;
        qn.z = (qv.z - mu) * rstd * g.z + be.z;
        qn.w = (qv.w - mu) * rstd * g.w + be.w;
        *reinterpret_cast<float4*>(&s_qn[t * CDIM + c]) = qn;
    }
    __syncthreads();

    // ---------- Phase A: qk[t][h][c] = sum_d qn[t][h*64+d] * Wk[c][h*64+d] ----------
    // wave (h = w&3, cg = w>>2 in {0,1}); lane owns columns c0 = cg*128+lane, c1 = c0+64.
    {
        const int h  = w & 3;
        const int cg = w >> 2;
        const int c0 = cg * 128 + lane;
        const int c1 = c0 + 64;
        const float* wk0 = Wk + (size_t)c0 * CDIM + h * DHEAD;
        const float* wk1 = Wk + (size_t)c1 * CDIM + h * DHEAD;
        float acc0[TB], acc1[TB];
        #pragma unroll
        for (int t = 0; t < TB; ++t) { acc0[t] = 0.0f; acc1[t] = 0.0f; }
        for (int d4 = 0; d4 < DHEAD / 4; ++d4) {
            const float4 wa = *reinterpret_cast<const float4*>(wk0 + d4 * 4);
            const float4 wb = *reinterpret_cast<const float4*>(wk1 + d4 * 4);
            #pragma unroll
            for (int t = 0; t < TB; ++t) {
                const float4 qv = *reinterpret_cast<const float4*>(
                    &s_qn[t * CDIM + h * DHEAD + d4 * 4]);   // broadcast read
                acc0[t] += qv.x*wa.x + qv.y*wa.y + qv.z*wa.z + qv.w*wa.w;
                acc1[t] += qv.x*wb.x + qv.y*wb.y + qv.z*wb.z + qv.w*wb.w;
            }
        }
        #pragma unroll
        for (int t = 0; t < TB; ++t) {
            s_qk[(t * NHEADS + h) * CDIM + c0] = acc0[t];
            s_qk[(t * NHEADS + h) * CDIM + c1] = acc1[t];
        }
    }
    __syncthreads();

    // ---------- Phase B: scores[t][h][n] = (1/8) sum_c ctx[t][n][c]*qk[t][h][c] ----------
    // wave w <-> token w; lane = (n = lane>>3, cs = lane&7). Each lane covers 32 c's
    // (8 float4 at c = i*32 + cs*4). Reduce over the 8 cs-lanes: 3 shfl levels (was 6).
    {
        const int t  = w;
        const int n  = lane >> 3;
        const int cs = lane & 7;
        const float* cb = ctx + ((size_t)(tok0 + t) * NV + n) * CDIM;
        float p0 = 0.f, p1 = 0.f, p2 = 0.f, p3 = 0.f;
        #pragma unroll
        for (int i = 0; i < 8; ++i) {
            const int c = i * 32 + cs * 4;
            const float4 cv = *reinterpret_cast<const float4*>(cb + c);
            const float4 k0 = *reinterpret_cast<const float4*>(&s_qk[(t*NHEADS+0)*CDIM + c]);
            const float4 k1 = *reinterpret_cast<const float4*>(&s_qk[(t*NHEADS+1)*CDIM + c]);
            const float4 k2 = *reinterpret_cast<const float4*>(&s_qk[(t*NHEADS+2)*CDIM + c]);
            const float4 k3 = *reinterpret_cast<const float4*>(&s_qk[(t*NHEADS+3)*CDIM + c]);
            p0 += cv.x*k0.x + cv.y*k0.y + cv.z*k0.z + cv.w*k0.w;
            p1 += cv.x*k1.x + cv.y*k1.y + cv.z*k1.z + cv.w*k1.w;
            p2 += cv.x*k2.x + cv.y*k2.y + cv.z*k2.z + cv.w*k2.w;
            p3 += cv.x*k3.x + cv.y*k3.y + cv.z*k3.z + cv.w*k3.w;
        }
        #pragma unroll
        for (int off = 4; off >= 1; off >>= 1) {
            p0 += __shfl_xor(p0, off);
            p1 += __shfl_xor(p1, off);
            p2 += __shfl_xor(p2, off);
            p3 += __shfl_xor(p3, off);
        }
        if (cs == 0) {
            s_sc[(t*NV + n)*NHEADS + 0] = p0 * 0.125f;
            s_sc[(t*NV + n)*NHEADS + 1] = p1 * 0.125f;
            s_sc[(t*NV + n)*NHEADS + 2] = p2 * 0.125f;
            s_sc[(t*NV + n)*NHEADS + 3] = p3 * 0.125f;
        }
    }
    __syncthreads();

    // ---------- Phase SM: softmax over n per (t,h); zero output accumulator ----------
    float* s_out = s_qn;   // s_qn dead after phase A
    {
        float4 z; z.x = z.y = z.z = z.w = 0.0f;
        reinterpret_cast<float4*>(s_out)[tid] = z;   // 512 threads * 4 = 2048 = TB*CDIM
        if (tid < TB * NHEADS) {
            const int t = tid >> 2;
            const int h = tid & 3;
            float sc[NV];
            float m = -1e30f;
            #pragma unroll
            for (int n = 0; n < NV; ++n) {
                sc[n] = s_sc[(t*NV + n)*NHEADS + h];
                m = fmaxf(m, sc[n]);
            }
            float sum = 0.0f;
            #pragma unroll
            for (int n = 0; n < NV; ++n) { sc[n] = __expf(sc[n] - m); sum += sc[n]; }
            const float inv = 1.0f / sum;
            const int tok = tok0 + t;
            const int b = tok >> 13;
            const int l = tok & (LSEQ - 1);
            float* pdst = probs_out + (((size_t)b * NHEADS + h) * LSEQ + l) * NV;
            #pragma unroll
            for (int n = 0; n < NV; ++n) {
                const float p = sc[n] * inv;
                s_sc[(t*NV + n)*NHEADS + h] = p;
                pdst[n] = p;
            }
        }
    }
    __syncthreads();

    // ---------- Phase C: wctx[t][h][c] = sum_n probs[t][h][n]*ctx[t][n][c] -> s_qk ----------
    // wave w <-> token w; ctx re-read is L1/L2-hot (tile just touched in phase B).
    {
        const int t = w;
        const float* cbase = ctx + ((size_t)(tok0 + t) * NV) * CDIM;
        float4 a0, a1, a2, a3;
        a0.x=a0.y=a0.z=a0.w=0.f; a1=a0; a2=a0; a3=a0;
        for (int n = 0; n < NV; ++n) {
            const float4 pr = *reinterpret_cast<const float4*>(&s_sc[(t*NV + n)*NHEADS]);
            const float4 cv = *reinterpret_cast<const float4*>(cbase + (size_t)n * CDIM + lane * 4);
            a0.x += pr.x*cv.x; a0.y += pr.x*cv.y; a0.z += pr.x*cv.z; a0.w += pr.x*cv.w;
            a1.x += pr.y*cv.x; a1.y += pr.y*cv.y; a1.z += pr.y*cv.z; a1.w += pr.y*cv.w;
            a2.x += pr.z*cv.x; a2.y += pr.z*cv.y; a2.z += pr.z*cv.z; a2.w += pr.z*cv.w;
            a3.x += pr.w*cv.x; a3.y += pr.w*cv.y; a3.z += pr.w*cv.z; a3.w += pr.w*cv.w;
        }
        *reinterpret_cast<float4*>(&s_qk[(t*NHEADS + 0)*CDIM + lane*4]) = a0;
        *reinterpret_cast<float4*>(&s_qk[(t*NHEADS + 1)*CDIM + lane*4]) = a1;
        *reinterpret_cast<float4*>(&s_qk[(t*NHEADS + 2)*CDIM + lane*4]) = a2;
        *reinterpret_cast<float4*>(&s_qk[(t*NHEADS + 3)*CDIM + lane*4]) = a3;
    }
    __syncthreads();

    // ---------- Phase D1: out[t][h*64+d] += sum_{c in cg block} wctx[t][h][c]*Wv[c][h*64+d] ----------
    // wave (h = w&3, cg = w>>2); lane = d. Cross-wave (2-way cg) combine via LDS float atomics.
    {
        const int h  = w & 3;
        const int cg = w >> 2;
        float acc[TB];
        #pragma unroll
        for (int t = 0; t < TB; ++t) acc[t] = 0.0f;
        const float* wvbase = Wv + h * DHEAD + lane;
        for (int c4 = 0; c4 < 32; ++c4) {
            const int c = cg * 128 + c4 * 4;
            const float wv0 = wvbase[(size_t)(c + 0) * CDIM];
            const float wv1 = wvbase[(size_t)(c + 1) * CDIM];
            const float wv2 = wvbase[(size_t)(c + 2) * CDIM];
            const float wv3 = wvbase[(size_t)(c + 3) * CDIM];
            #pragma unroll
            for (int t = 0; t < TB; ++t) {
                const float4 wc = *reinterpret_cast<const float4*>(
                    &s_qk[(t*NHEADS + h)*CDIM + c]);   // broadcast read
                acc[t] += wc.x*wv0 + wc.y*wv1 + wc.z*wv2 + wc.w*wv3;
            }
        }
        #pragma unroll
        for (int t = 0; t < TB; ++t)
            atomicAdd(&s_out[t * CDIM + h * DHEAD + lane], acc[t]);
    }
    __syncthreads();

    // ---------- Phase D3: add bv, write out ----------
    {
        const int t = w;
        const int c = lane * 4;
        float4 o = *reinterpret_cast<const float4*>(&s_out[t * CDIM + c]);
        const float4 bvv = *reinterpret_cast<const float4*>(bv + c);
        o.x += bvv.x; o.y += bvv.y; o.z += bvv.z; o.w += bvv.w;
        *reinterpret_cast<float4*>(out + (size_t)(tok0 + t) * CDIM + c) = o;
    }
}

extern "C" void kernel_launch(void* const* d_in, const int* in_sizes, int n_in,
                              void* d_out, int out_size, void* d_ws, size_t ws_size,
                              hipStream_t stream) {
    const float* q     = (const float*)d_in[0];
    const float* ctx   = (const float*)d_in[1];
    const float* Wk    = (const float*)d_in[2];
    // d_in[3] = bk: adds a per-(t,h) constant to all Nv scores -> cancels in softmax; unused.
    const float* Wv    = (const float*)d_in[4];
    const float* bv    = (const float*)d_in[5];
    const float* gamma = (const float*)d_in[6];
    const float* beta  = (const float*)d_in[7];

    float* out   = (float*)d_out;
    float* probs = out + (size_t)NB * LSEQ * CDIM;

    const int n_tok = NB * LSEQ;               // 32768
    dim3 grid(n_tok / TB), block(512);
    hipLaunchKernelGGL(triplane_fused, grid, block, 0, stream,
                       q, ctx, Wk, Wv, bv, gamma, beta, out, probs);
}

// Round 3
// 163.970 us; speedup vs baseline: 2.9740x; 2.5357x over previous
//
#include <hip/hip_runtime.h>
#include <math.h>

#define TB     8       // tokens per workgroup
#define CDIM   256
#define NHEADS 4
#define DHEAD  64
#define NV     8
#define LSEQ   8192
#define NB     4

typedef short  bf16x8 __attribute__((ext_vector_type(8)));
typedef float  f32x4  __attribute__((ext_vector_type(4)));
typedef unsigned short u16;

// ---- bf16 split helpers (RNE) ----
static __device__ __forceinline__ u16 f2bf(float x) {
    unsigned u = __float_as_uint(x);
    unsigned r = ((u >> 16) & 1u) + 0x7fffu;
    return (u16)((u + r) >> 16);
}
static __device__ __forceinline__ float bf2f(u16 h) {
    return __uint_as_float(((unsigned)h) << 16);
}

// =====================================================================
// Pre-pass: convert Wk, Wv (fp32) into MFMA B-fragment-ready bf16 hi/lo
// layouts in workspace.
//  wkf (phase A, B[k=d][n=c] = Wk[c][h*64+d]):
//    unit = (((h*2+kc)*16+nt)*2+s)*64 + lane ; 8 bf16 per unit, k=(l>>4)*8+j
//    4h*2kc*16nt*2s*64lane = 16384 units  (round-2 bug: bound was 8192 ->
//    heads 2-3 never written; fixed)
//  wvf (phase D, B[k=c][n=d] = Wv[c][h*64+d]):
//    unit = (((h*8+kc)*4+nt)*2+s)*64 + lane ; 4h*8kc*4nt*2s*64lane = 16384 units
// =====================================================================
__global__ __launch_bounds__(256) void prep_frags(
    const float* __restrict__ Wk, const float* __restrict__ Wv,
    u16* __restrict__ wkf, u16* __restrict__ wvf)
{
    const int tid = blockIdx.x * 256 + threadIdx.x;
    union { u16 u[8]; uint4 v; } pk;
    if (tid < 16384) {                      // wkf
        int l = tid & 63; int r = tid >> 6;
        const int s  = r & 1;  r >>= 1;
        const int nt = r & 15; r >>= 4;
        const int kc = r & 1;  r >>= 1;
        const int h  = r & 3;
        const int c     = nt * 16 + (l & 15);
        const int dbase = h * DHEAD + kc * 32 + (l >> 4) * 8;
        #pragma unroll
        for (int j = 0; j < 8; ++j) {
            const float x  = Wk[(size_t)c * CDIM + dbase + j];
            const u16 hi = f2bf(x);
            const u16 lo = f2bf(x - bf2f(hi));
            pk.u[j] = s ? lo : hi;
        }
        *reinterpret_cast<uint4*>(wkf + (size_t)tid * 8) = pk.v;
    } else if (tid < 32768) {               // wvf
        int t2 = tid - 16384;
        int l = t2 & 63; int r = t2 >> 6;
        const int s  = r & 1; r >>= 1;
        const int nt = r & 3; r >>= 2;
        const int kc = r & 7; r >>= 3;
        const int h  = r & 3;
        const int d     = h * DHEAD + nt * 16 + (l & 15);
        const int cbase = kc * 32 + (l >> 4) * 8;
        #pragma unroll
        for (int j = 0; j < 8; ++j) {
            const float x  = Wv[(size_t)(cbase + j) * CDIM + d];
            const u16 hi = f2bf(x);
            const u16 lo = f2bf(x - bf2f(hi));
            pk.u[j] = s ? lo : hi;
        }
        *reinterpret_cast<uint4*>(wvf + (size_t)t2 * 8) = pk.v;
    }
}

// =====================================================================
// Main fused kernel. Phases A and D use mfma_f32_16x16x32_bf16 with
// split-bf16 (hi+lo) operands: err ~2e-4 per 256-term dot (fp32-class).
// M=16 tile holds TB=8 real tokens; rows 8-15 duplicate 0-7 (row=lane&7)
// and are never written back.
// LDS ~41KB -> 3 blocks/CU (24 waves, as round 1).
// =====================================================================
__global__ __launch_bounds__(512, 6) void triplane_fused(
    const float* __restrict__ q,
    const float* __restrict__ ctx,
    const u16*   __restrict__ wkf,
    const u16*   __restrict__ wvf,
    const float* __restrict__ bv,
    const float* __restrict__ gamma,
    const float* __restrict__ beta,
    float* __restrict__ out,
    float* __restrict__ probs_out)
{
    __shared__ __align__(16) float s_qk[TB * NHEADS * CDIM];  // 32KB fp32 qk; reused as wctx bf16 hi/lo
    __shared__ __align__(16) u16   s_qnh[TB * CDIM];          // 4KB  qn hi (XOR-swizzled rows)
    __shared__ __align__(16) u16   s_qnl[TB * CDIM];          // 4KB  qn lo
    __shared__ float s_sc[TB * NV * NHEADS];                  // 1KB  scores->probs [t][n][h]

    const int tid  = threadIdx.x;
    const int w    = tid >> 6;    // wave 0..7
    const int lane = tid & 63;
    const int tok0 = blockIdx.x * TB;

    // ---------- Phase 0: LayerNorm(q) -> bf16 hi/lo in swizzled LDS ----------
    {
        const int t = w;
        const int c = lane * 4;
        const float4 qv = *reinterpret_cast<const float4*>(q + (size_t)(tok0 + t) * CDIM + c);
        float s  = qv.x + qv.y + qv.z + qv.w;
        float s2 = qv.x*qv.x + qv.y*qv.y + qv.z*qv.z + qv.w*qv.w;
        #pragma unroll
        for (int off = 32; off >= 1; off >>= 1) {
            s  += __shfl_xor(s,  off);
            s2 += __shfl_xor(s2, off);
        }
        const float mu   = s  * (1.0f / CDIM);
        const float var  = s2 * (1.0f / CDIM) - mu * mu;
        const float rstd = rsqrtf(var + 1e-5f);
        const float4 g  = *reinterpret_cast<const float4*>(gamma + c);
        const float4 be = *reinterpret_cast<const float4*>(beta + c);
        float qn[4];
        qn[0] = (qv.x - mu) * rstd * g.x + be.x;
        qn[1] = (qv.y - mu) * rstd * g.y + be.y;
        qn[2] = (qv.z - mu) * rstd * g.z + be.z;
        qn[3] = (qv.w - mu) * rstd * g.w + be.w;
        ushort4 vh, vl;
        u16 h0 = f2bf(qn[0]); vh.x = h0; vl.x = f2bf(qn[0] - bf2f(h0));
        u16 h1 = f2bf(qn[1]); vh.y = h1; vl.y = f2bf(qn[1] - bf2f(h1));
        u16 h2 = f2bf(qn[2]); vh.z = h2; vl.z = f2bf(qn[2] - bf2f(h2));
        u16 h3 = f2bf(qn[3]); vh.w = h3; vl.w = f2bf(qn[3] - bf2f(h3));
        const int off = t * 512 + ((lane * 8) ^ (t << 4));   // byte offset, 8B aligned
        *reinterpret_cast<ushort4*>(reinterpret_cast<char*>(s_qnh) + off) = vh;
        *reinterpret_cast<ushort4*>(reinterpret_cast<char*>(s_qnl) + off) = vl;
    }
    __syncthreads();

    // ---------- Phase A (MFMA): qk[t][h][c] = qn_h[t][:] . Wk_h^T[:][c] ----------
    // wave (h = w&3, ch = w>>2): N-half of 128 c's. M=16 (8 dup), K=64 (2 chunks).
    {
        const int h  = w & 3;
        const int ch = w >> 2;
        const int arow = lane & 7;       // dup rows 8-15 <- 0-7
        const int akq  = lane >> 4;      // k quarter
        bf16x8 aH[2], aL[2];
        #pragma unroll
        for (int kc = 0; kc < 2; ++kc) {
            const int intra = (h * DHEAD + kc * 32 + akq * 8) * 2;  // 16B aligned
            const int off   = arow * 512 + (intra ^ (arow << 4));
            aH[kc] = *reinterpret_cast<const bf16x8*>(reinterpret_cast<const char*>(s_qnh) + off);
            aL[kc] = *reinterpret_cast<const bf16x8*>(reinterpret_cast<const char*>(s_qnl) + off);
        }
        #pragma unroll
        for (int nt = 0; nt < 8; ++nt) {
            f32x4 acc = {0.f, 0.f, 0.f, 0.f};
            #pragma unroll
            for (int kc = 0; kc < 2; ++kc) {
                const u16* p = wkf + ((size_t)(h * 4096 + kc * 2048 + (ch * 8 + nt) * 128) + lane) * 8;
                const bf16x8 bH = *reinterpret_cast<const bf16x8*>(p);
                const bf16x8 bL = *reinterpret_cast<const bf16x8*>(p + 512);
                acc = __builtin_amdgcn_mfma_f32_16x16x32_bf16(aH[kc], bH, acc, 0, 0, 0);
                acc = __builtin_amdgcn_mfma_f32_16x16x32_bf16(aL[kc], bH, acc, 0, 0, 0);
                acc = __builtin_amdgcn_mfma_f32_16x16x32_bf16(aH[kc], bL, acc, 0, 0, 0);
            }
            if (lane < 32) {
                const int tt = (lane >> 4) * 4;               // 0 or 4
                const int cc = ch * 128 + nt * 16 + (lane & 15);
                #pragma unroll
                for (int reg = 0; reg < 4; ++reg)
                    s_qk[((tt + reg) * NHEADS + h) * CDIM + cc] = acc[reg];
            }
        }
    }
    __syncthreads();

    // ---------- Phase B: scores[t][h][n] = (1/8) sum_c ctx[t][n][c]*qk[t][h][c] ----------
    {
        const int t  = w;
        const int n  = lane >> 3;
        const int cs = lane & 7;
        const float* cb = ctx + ((size_t)(tok0 + t) * NV + n) * CDIM;
        float p0 = 0.f, p1 = 0.f, p2 = 0.f, p3 = 0.f;
        #pragma unroll
        for (int i = 0; i < 8; ++i) {
            const int c = i * 32 + cs * 4;
            const float4 cv = *reinterpret_cast<const float4*>(cb + c);
            const float4 k0 = *reinterpret_cast<const float4*>(&s_qk[(t*NHEADS+0)*CDIM + c]);
            const float4 k1 = *reinterpret_cast<const float4*>(&s_qk[(t*NHEADS+1)*CDIM + c]);
            const float4 k2 = *reinterpret_cast<const float4*>(&s_qk[(t*NHEADS+2)*CDIM + c]);
            const float4 k3 = *reinterpret_cast<const float4*>(&s_qk[(t*NHEADS+3)*CDIM + c]);
            p0 += cv.x*k0.x + cv.y*k0.y + cv.z*k0.z + cv.w*k0.w;
            p1 += cv.x*k1.x + cv.y*k1.y + cv.z*k1.z + cv.w*k1.w;
            p2 += cv.x*k2.x + cv.y*k2.y + cv.z*k2.z + cv.w*k2.w;
            p3 += cv.x*k3.x + cv.y*k3.y + cv.z*k3.z + cv.w*k3.w;
        }
        #pragma unroll
        for (int off = 4; off >= 1; off >>= 1) {
            p0 += __shfl_xor(p0, off);
            p1 += __shfl_xor(p1, off);
            p2 += __shfl_xor(p2, off);
            p3 += __shfl_xor(p3, off);
        }
        if (cs == 0) {
            s_sc[(t*NV + n)*NHEADS + 0] = p0 * 0.125f;
            s_sc[(t*NV + n)*NHEADS + 1] = p1 * 0.125f;
            s_sc[(t*NV + n)*NHEADS + 2] = p2 * 0.125f;
            s_sc[(t*NV + n)*NHEADS + 3] = p3 * 0.125f;
        }
    }
    __syncthreads();

    // ---------- Phase SM: softmax over n per (t,h), write probs ----------
    {
        if (tid < TB * NHEADS) {
            const int t = tid >> 2;
            const int h = tid & 3;
            float sc[NV];
            float m = -1e30f;
            #pragma unroll
            for (int n = 0; n < NV; ++n) {
                sc[n] = s_sc[(t*NV + n)*NHEADS + h];
                m = fmaxf(m, sc[n]);
            }
            float sum = 0.0f;
            #pragma unroll
            for (int n = 0; n < NV; ++n) { sc[n] = __expf(sc[n] - m); sum += sc[n]; }
            const float inv = 1.0f / sum;
            const int tok = tok0 + t;
            const int b = tok >> 13;
            const int l = tok & (LSEQ - 1);
            float* pdst = probs_out + (((size_t)b * NHEADS + h) * LSEQ + l) * NV;
            #pragma unroll
            for (int n = 0; n < NV; ++n) {
                const float p = sc[n] * inv;
                s_sc[(t*NV + n)*NHEADS + h] = p;
                pdst[n] = p;
            }
        }
    }
    __syncthreads();

    // ---------- Phase C: wctx[h][t][c] = sum_n probs*ctx -> bf16 hi/lo into s_qk alias ----------
    {
        const int t = w;
        const float* cbase = ctx + ((size_t)(tok0 + t) * NV) * CDIM;
        float4 a0, a1, a2, a3;
        a0.x=a0.y=a0.z=a0.w=0.f; a1=a0; a2=a0; a3=a0;
        for (int n = 0; n < NV; ++n) {
            const float4 pr = *reinterpret_cast<const float4*>(&s_sc[(t*NV + n)*NHEADS]);
            const float4 cv = *reinterpret_cast<const float4*>(cbase + (size_t)n * CDIM + lane * 4);
            a0.x += pr.x*cv.x; a0.y += pr.x*cv.y; a0.z += pr.x*cv.z; a0.w += pr.x*cv.w;
            a1.x += pr.y*cv.x; a1.y += pr.y*cv.y; a1.z += pr.y*cv.z; a1.w += pr.y*cv.w;
            a2.x += pr.z*cv.x; a2.y += pr.z*cv.y; a2.z += pr.z*cv.z; a2.w += pr.z*cv.w;
            a3.x += pr.w*cv.x; a3.y += pr.w*cv.y; a3.z += pr.w*cv.z; a3.w += pr.w*cv.w;
        }
        __syncthreads();   // s_qk (fp32 qk) fully consumed in B; safe to overwrite as bf16
        char* wch = reinterpret_cast<char*>(s_qk);            // hi region [0,16384)
        char* wcl = wch + 16384;                              // lo region
        const float4 av[4] = {a0, a1, a2, a3};
        const int xo = (lane * 8) ^ (t << 4);
        #pragma unroll
        for (int h = 0; h < 4; ++h) {
            const float4 v = av[h];
            ushort4 vh, vl;
            u16 h0 = f2bf(v.x); vh.x = h0; vl.x = f2bf(v.x - bf2f(h0));
            u16 h1 = f2bf(v.y); vh.y = h1; vl.y = f2bf(v.y - bf2f(h1));
            u16 h2 = f2bf(v.z); vh.z = h2; vl.z = f2bf(v.z - bf2f(h2));
            u16 h3 = f2bf(v.w); vh.w = h3; vl.w = f2bf(v.w - bf2f(h3));
            const int off = (h * TB + t) * 512 + xo;
            *reinterpret_cast<ushort4*>(wch + off) = vh;
            *reinterpret_cast<ushort4*>(wcl + off) = vl;
        }
    }
    __syncthreads();

    // ---------- Phase D (MFMA): out[t][h*64+d] = wctx_h[t][:] . Wv_h[:][d] + bv ----------
    // wave (h = w&3, dh = w>>2): 2 N-tiles of 16 d's. K=256 (8 chunks).
    {
        const int h  = w & 3;
        const int dh = w >> 2;
        const int arow = lane & 7;
        const int akq  = lane >> 4;
        const char* wch = reinterpret_cast<const char*>(s_qk);
        const char* wcl = wch + 16384;
        #pragma unroll
        for (int nt2 = 0; nt2 < 2; ++nt2) {
            const int nt = dh * 2 + nt2;
            f32x4 acc = {0.f, 0.f, 0.f, 0.f};
            #pragma unroll
            for (int kc = 0; kc < 8; ++kc) {
                const int intra = (kc * 32 + akq * 8) * 2;
                const int off   = (h * TB + arow) * 512 + (intra ^ (arow << 4));
                const bf16x8 aH = *reinterpret_cast<const bf16x8*>(wch + off);
                const bf16x8 aL = *reinterpret_cast<const bf16x8*>(wcl + off);
                const u16* p = wvf + ((size_t)(h * 4096 + kc * 512 + nt * 128) + lane) * 8;
                const bf16x8 bH = *reinterpret_cast<const bf16x8*>(p);
                const bf16x8 bL = *reinterpret_cast<const bf16x8*>(p + 512);
                acc = __builtin_amdgcn_mfma_f32_16x16x32_bf16(aH, bH, acc, 0, 0, 0);
                acc = __builtin_amdgcn_mfma_f32_16x16x32_bf16(aL, bH, acc, 0, 0, 0);
                acc = __builtin_amdgcn_mfma_f32_16x16x32_bf16(aH, bL, acc, 0, 0, 0);
            }
            if (lane < 32) {
                const int tt = (lane >> 4) * 4;
                const int d  = h * DHEAD + nt * 16 + (lane & 15);
                const float bvv = bv[d];
                #pragma unroll
                for (int reg = 0; reg < 4; ++reg)
                    out[(size_t)(tok0 + tt + reg) * CDIM + d] = acc[reg] + bvv;
            }
        }
    }
}

// =====================================================================
// Fallback (round-1 vector kernel) if workspace is too small.
// =====================================================================
__global__ __launch_bounds__(512, 6) void triplane_fused_v1(
    const float* __restrict__ q, const float* __restrict__ ctx,
    const float* __restrict__ Wk, const float* __restrict__ Wv,
    const float* __restrict__ bv, const float* __restrict__ gamma,
    const float* __restrict__ beta, float* __restrict__ out,
    float* __restrict__ probs_out)
{
    __shared__ float s_qn[TB * CDIM];
    __shared__ float s_qk[TB * NHEADS * CDIM];
    __shared__ float s_sc[TB * NV * NHEADS];
    const int tid  = threadIdx.x;
    const int w    = tid >> 6;
    const int lane = tid & 63;
    const int tok0 = blockIdx.x * TB;
    {
        const int t = w; const int c = lane * 4;
        const float4 qv = *reinterpret_cast<const float4*>(q + (size_t)(tok0 + t) * CDIM + c);
        float s  = qv.x + qv.y + qv.z + qv.w;
        float s2 = qv.x*qv.x + qv.y*qv.y + qv.z*qv.z + qv.w*qv.w;
        #pragma unroll
        for (int off = 32; off >= 1; off >>= 1) { s += __shfl_xor(s, off); s2 += __shfl_xor(s2, off); }
        const float mu = s * (1.0f/CDIM);
        const float var = s2 * (1.0f/CDIM) - mu*mu;
        const float rstd = rsqrtf(var + 1e-5f);
        const float4 g  = *reinterpret_cast<const float4*>(gamma + c);
        const float4 be = *reinterpret_cast<const float4*>(beta + c);
        float4 qn;
        qn.x=(qv.x-mu)*rstd*g.x+be.x; qn.y=(qv.y-mu)*rstd*g.y+be.y;
        qn.z=(qv.z-mu)*rstd*g.z+be.z; qn.w=(qv.w-mu)*rstd*g.w+be.w;
        *reinterpret_cast<float4*>(&s_qn[t*CDIM + c]) = qn;
    }
    __syncthreads();
    {
        const int h = w & 3; const int cg = w >> 2;
        const int c0 = cg*128 + lane; const int c1 = c0 + 64;
        const float* wk0 = Wk + (size_t)c0*CDIM + h*DHEAD;
        const float* wk1 = Wk + (size_t)c1*CDIM + h*DHEAD;
        float acc0[TB], acc1[TB];
        #pragma unroll
        for (int t = 0; t < TB; ++t) { acc0[t]=0.f; acc1[t]=0.f; }
        for (int d4 = 0; d4 < DHEAD/4; ++d4) {
            const float4 wa = *reinterpret_cast<const float4*>(wk0 + d4*4);
            const float4 wb = *reinterpret_cast<const float4*>(wk1 + d4*4);
            #pragma unroll
            for (int t = 0; t < TB; ++t) {
                const float4 qv = *reinterpret_cast<const float4*>(&s_qn[t*CDIM + h*DHEAD + d4*4]);
                acc0[t] += qv.x*wa.x + qv.y*wa.y + qv.z*wa.z + qv.w*wa.w;
                acc1[t] += qv.x*wb.x + qv.y*wb.y + qv.z*wb.z + qv.w*wb.w;
            }
        }
        #pragma unroll
        for (int t = 0; t < TB; ++t) {
            s_qk[(t*NHEADS+h)*CDIM + c0] = acc0[t];
            s_qk[(t*NHEADS+h)*CDIM + c1] = acc1[t];
        }
    }
    __syncthreads();
    {
        const int t = w; const int n = lane >> 3; const int cs = lane & 7;
        const float* cb = ctx + ((size_t)(tok0 + t)*NV + n)*CDIM;
        float p0=0,p1=0,p2=0,p3=0;
        #pragma unroll
        for (int i = 0; i < 8; ++i) {
            const int c = i*32 + cs*4;
            const float4 cv = *reinterpret_cast<const float4*>(cb + c);
            const float4 k0 = *reinterpret_cast<const float4*>(&s_qk[(t*NHEADS+0)*CDIM + c]);
            const float4 k1 = *reinterpret_cast<const float4*>(&s_qk[(t*NHEADS+1)*CDIM + c]);
            const float4 k2 = *reinterpret_cast<const float4*>(&s_qk[(t*NHEADS+2)*CDIM + c]);
            const float4 k3 = *reinterpret_cast<const float4*>(&s_qk[(t*NHEADS+3)*CDIM + c]);
            p0 += cv.x*k0.x+cv.y*k0.y+cv.z*k0.z+cv.w*k0.w;
            p1 += cv.x*k1.x+cv.y*k1.y+cv.z*k1.z+cv.w*k1.w;
            p2 += cv.x*k2.x+cv.y*k2.y+cv.z*k2.z+cv.w*k2.w;
            p3 += cv.x*k3.x+cv.y*k3.y+cv.z*k3.z+cv.w*k3.w;
        }
        #pragma unroll
        for (int off = 4; off >= 1; off >>= 1) {
            p0 += __shfl_xor(p0, off); p1 += __shfl_xor(p1, off);
            p2 += __shfl_xor(p2, off); p3 += __shfl_xor(p3, off);
        }
        if (cs == 0) {
            s_sc[(t*NV+n)*NHEADS+0] = p0*0.125f; s_sc[(t*NV+n)*NHEADS+1] = p1*0.125f;
            s_sc[(t*NV+n)*NHEADS+2] = p2*0.125f; s_sc[(t*NV+n)*NHEADS+3] = p3*0.125f;
        }
    }
    __syncthreads();
    float* s_out = s_qn;
    {
        float4 z; z.x=z.y=z.z=z.w=0.f;
        reinterpret_cast<float4*>(s_out)[tid] = z;
        if (tid < TB*NHEADS) {
            const int t = tid >> 2; const int h = tid & 3;
            float sc[NV]; float m = -1e30f;
            #pragma unroll
            for (int n = 0; n < NV; ++n) { sc[n] = s_sc[(t*NV+n)*NHEADS+h]; m = fmaxf(m, sc[n]); }
            float sum = 0.f;
            #pragma unroll
            for (int n = 0; n < NV; ++n) { sc[n] = __expf(sc[n]-m); sum += sc[n]; }
            const float inv = 1.f/sum;
            const int tok = tok0 + t; const int b = tok >> 13; const int l = tok & (LSEQ-1);
            float* pdst = probs_out + (((size_t)b*NHEADS + h)*LSEQ + l)*NV;
            #pragma unroll
            for (int n = 0; n < NV; ++n) { const float p = sc[n]*inv; s_sc[(t*NV+n)*NHEADS+h] = p; pdst[n] = p; }
        }
    }
    __syncthreads();
    {
        const int t = w;
        const float* cbase = ctx + ((size_t)(tok0 + t)*NV)*CDIM;
        float4 a0,a1,a2,a3; a0.x=a0.y=a0.z=a0.w=0.f; a1=a0; a2=a0; a3=a0;
        for (int n = 0; n < NV; ++n) {
            const float4 pr = *reinterpret_cast<const float4*>(&s_sc[(t*NV+n)*NHEADS]);
            const float4 cv = *reinterpret_cast<const float4*>(cbase + (size_t)n*CDIM + lane*4);
            a0.x+=pr.x*cv.x; a0.y+=pr.x*cv.y; a0.z+=pr.x*cv.z; a0.w+=pr.x*cv.w;
            a1.x+=pr.y*cv.x; a1.y+=pr.y*cv.y; a1.z+=pr.y*cv.z; a1.w+=pr.y*cv.w;
            a2.x+=pr.z*cv.x; a2.y+=pr.z*cv.y; a2.z+=pr.z*cv.z; a2.w+=pr.z*cv.w;
            a3.x+=pr.w*cv.x; a3.y+=pr.w*cv.y; a3.z+=pr.w*cv.z; a3.w+=pr.w*cv.w;
        }
        *reinterpret_cast<float4*>(&s_qk[(t*NHEADS+0)*CDIM + lane*4]) = a0;
        *reinterpret_cast<float4*>(&s_qk[(t*NHEADS+1)*CDIM + lane*4]) = a1;
        *reinterpret_cast<float4*>(&s_qk[(t*NHEADS+2)*CDIM + lane*4]) = a2;
        *reinterpret_cast<float4*>(&s_qk[(t*NHEADS+3)*CDIM + lane*4]) = a3;
    }
    __syncthreads();
    {
        const int h = w & 3; const int cg = w >> 2;
        float acc[TB];
        #pragma unroll
        for (int t = 0; t < TB; ++t) acc[t] = 0.f;
        const float* wvbase = Wv + h*DHEAD + lane;
        for (int c4 = 0; c4 < 32; ++c4) {
            const int c = cg*128 + c4*4;
            const float wv0 = wvbase[(size_t)(c+0)*CDIM];
            const float wv1 = wvbase[(size_t)(c+1)*CDIM];
            const float wv2 = wvbase[(size_t)(c+2)*CDIM];
            const float wv3 = wvbase[(size_t)(c+3)*CDIM];
            #pragma unroll
            for (int t = 0; t < TB; ++t) {
                const float4 wc = *reinterpret_cast<const float4*>(&s_qk[(t*NHEADS+h)*CDIM + c]);
                acc[t] += wc.x*wv0 + wc.y*wv1 + wc.z*wv2 + wc.w*wv3;
            }
        }
        #pragma unroll
        for (int t = 0; t < TB; ++t) atomicAdd(&s_out[t*CDIM + h*DHEAD + lane], acc[t]);
    }
    __syncthreads();
    {
        const int t = w; const int c = lane * 4;
        float4 o = *reinterpret_cast<const float4*>(&s_out[t*CDIM + c]);
        const float4 bvv = *reinterpret_cast<const float4*>(bv + c);
        o.x += bvv.x; o.y += bvv.y; o.z += bvv.z; o.w += bvv.w;
        *reinterpret_cast<float4*>(out + (size_t)(tok0 + t)*CDIM + c) = o;
    }
}

extern "C" void kernel_launch(void* const* d_in, const int* in_sizes, int n_in,
                              void* d_out, int out_size, void* d_ws, size_t ws_size,
                              hipStream_t stream) {
    const float* q     = (const float*)d_in[0];
    const float* ctx   = (const float*)d_in[1];
    const float* Wk    = (const float*)d_in[2];
    // d_in[3] = bk: per-(t,h) constant across the Nv scores -> cancels in softmax; unused.
    const float* Wv    = (const float*)d_in[4];
    const float* bv    = (const float*)d_in[5];
    const float* gamma = (const float*)d_in[6];
    const float* beta  = (const float*)d_in[7];

    float* out   = (float*)d_out;
    float* probs = out + (size_t)NB * LSEQ * CDIM;

    const int n_tok = NB * LSEQ;               // 32768
    const size_t ws_need = (size_t)2 * 131072 * sizeof(u16);   // 512 KB

    if (d_ws != nullptr && ws_size >= ws_need) {
        u16* wkf = (u16*)d_ws;
        u16* wvf = wkf + 131072;
        hipLaunchKernelGGL(prep_frags, dim3(128), dim3(256), 0, stream, Wk, Wv, wkf, wvf);
        hipLaunchKernelGGL(triplane_fused, dim3(n_tok / TB), dim3(512), 0, stream,
                           q, ctx, wkf, wvf, bv, gamma, beta, out, probs);
    } else {
        hipLaunchKernelGGL(triplane_fused_v1, dim3(n_tok / TB), dim3(512), 0, stream,
                           q, ctx, Wk, Wv, bv, gamma, beta, out, probs);
    }
}